// Round 1
// baseline (876.137 us; speedup 1.0000x reference)
//
#include <hip/hip_runtime.h>
#include <stdint.h>

#define BN_EPS 1e-5f

typedef __attribute__((ext_vector_type(8))) short s16x8;
typedef __attribute__((ext_vector_type(16))) float f32x16;
typedef unsigned short ushort_t;

__device__ __forceinline__ ushort_t f2bf(float x) {
    uint32_t u = __float_as_uint(x);
    u += 0x7fff + ((u >> 16) & 1);   // round-to-nearest-even
    return (ushort_t)(u >> 16);
}
__device__ __forceinline__ float bf2f(ushort_t h) {
    return __uint_as_float(((uint32_t)h) << 16);
}

// ---------------- CSR build ----------------
__global__ void k_deg(const int* __restrict__ dst, int E, int* __restrict__ deg) {
    int i = blockIdx.x * blockDim.x + threadIdx.x;
    int st = gridDim.x * blockDim.x;
    for (; i < E; i += st) atomicAdd(&deg[dst[i]], 1);
}

__global__ void k_blocksum(const int* __restrict__ deg, int N, int* __restrict__ bsum) {
    __shared__ int sd[256];
    int b = blockIdx.x, t = threadIdx.x;
    int base = b << 10;
    int s = 0;
    for (int j = t; j < 1024; j += 256) { int i = base + j; if (i < N) s += deg[i]; }
    sd[t] = s; __syncthreads();
    for (int off = 128; off > 0; off >>= 1) { if (t < off) sd[t] += sd[t + off]; __syncthreads(); }
    if (t == 0) bsum[b] = sd[0];
}

// single block, 128 threads; requires NB <= 128 (N=100000 -> NB=98)
__global__ void k_scanbsum(int* __restrict__ bsum, int NB, int* __restrict__ rowstart, int N) {
    __shared__ int sd[128];
    int t = threadIdx.x;
    int v = (t < NB) ? bsum[t] : 0;
    sd[t] = v; __syncthreads();
    for (int off = 1; off < 128; off <<= 1) {
        int y = (t >= off) ? sd[t - off] : 0;
        __syncthreads();
        sd[t] += y;
        __syncthreads();
    }
    if (t < NB) bsum[t] = (t == 0) ? 0 : sd[t - 1];   // exclusive block offsets
    if (t == 0) rowstart[N] = sd[127];                // total = E
}

__global__ void k_localscan(const int* __restrict__ deg, int N, const int* __restrict__ boff,
                            int* __restrict__ rowstart, int* __restrict__ cursor) {
    __shared__ int sd[256];
    int b = blockIdx.x, t = threadIdx.x;
    int base = (b << 10) + (t << 2);
    int v0 = 0, v1 = 0, v2 = 0, v3 = 0;
    if (base + 0 < N) v0 = deg[base + 0];
    if (base + 1 < N) v1 = deg[base + 1];
    if (base + 2 < N) v2 = deg[base + 2];
    if (base + 3 < N) v3 = deg[base + 3];
    sd[t] = v0 + v1 + v2 + v3; __syncthreads();
    for (int off = 1; off < 256; off <<= 1) {
        int y = (t >= off) ? sd[t - off] : 0;
        __syncthreads();
        sd[t] += y;
        __syncthreads();
    }
    int run = boff[b] + ((t == 0) ? 0 : sd[t - 1]);
    if (base + 0 < N) { rowstart[base + 0] = run; cursor[base + 0] = run; run += v0; }
    if (base + 1 < N) { rowstart[base + 1] = run; cursor[base + 1] = run; run += v1; }
    if (base + 2 < N) { rowstart[base + 2] = run; cursor[base + 2] = run; run += v2; }
    if (base + 3 < N) { rowstart[base + 3] = run; cursor[base + 3] = run; run += v3; }
}

__global__ void k_fill(const int* __restrict__ src, const int* __restrict__ dst, int E,
                       int* __restrict__ cursor, int* __restrict__ csr) {
    int i = blockIdx.x * blockDim.x + threadIdx.x;
    int st = gridDim.x * blockDim.x;
    for (; i < E; i += st) {
        int d = dst[i];
        int p = atomicAdd(&cursor[d], 1);
        csr[p] = src[i];
    }
}

// ---------------- aggregation: out = f(in[n]) + sum_nbr f(in[s]), f = id or bn+relu ----
// one wave per node; lane handles 2 channels (float2); writes bf16 hi/lo planes
template <bool BN>
__global__ void k_agg(const float* __restrict__ in, int N,
                      const int* __restrict__ rowstart, const int* __restrict__ csr,
                      const float* __restrict__ scale, const float* __restrict__ shift,
                      ushort_t* __restrict__ out_hi, ushort_t* __restrict__ out_lo) {
    int wave = (int)((blockIdx.x * (size_t)blockDim.x + threadIdx.x) >> 6);
    int lane = threadIdx.x & 63;
    if (wave >= N) return;
    int c = lane * 2;
    float sc0 = 0.f, sc1 = 0.f, sh0 = 0.f, sh1 = 0.f;
    if (BN) { sc0 = scale[c]; sc1 = scale[c + 1]; sh0 = shift[c]; sh1 = shift[c + 1]; }

    const float2* self = (const float2*)(in + (size_t)wave * 128 + c);
    float2 v = *self;
    float a0, a1;
    if (BN) { a0 = fmaxf(v.x * sc0 + sh0, 0.f); a1 = fmaxf(v.y * sc1 + sh1, 0.f); }
    else    { a0 = v.x; a1 = v.y; }

    int s0 = rowstart[wave], s1 = rowstart[wave + 1];
    for (int base = s0; base < s1; base += 64) {
        int m = s1 - base; if (m > 64) m = 64;
        int idx = (lane < m) ? csr[base + lane] : 0;
        int j = 0;
        for (; j + 4 <= m; j += 4) {
            int r0 = __shfl(idx, j, 64);
            int r1 = __shfl(idx, j + 1, 64);
            int r2 = __shfl(idx, j + 2, 64);
            int r3 = __shfl(idx, j + 3, 64);
            float2 u0 = *(const float2*)(in + (size_t)r0 * 128 + c);
            float2 u1 = *(const float2*)(in + (size_t)r1 * 128 + c);
            float2 u2 = *(const float2*)(in + (size_t)r2 * 128 + c);
            float2 u3 = *(const float2*)(in + (size_t)r3 * 128 + c);
            if (BN) {
                a0 += fmaxf(u0.x * sc0 + sh0, 0.f) + fmaxf(u1.x * sc0 + sh0, 0.f)
                    + fmaxf(u2.x * sc0 + sh0, 0.f) + fmaxf(u3.x * sc0 + sh0, 0.f);
                a1 += fmaxf(u0.y * sc1 + sh1, 0.f) + fmaxf(u1.y * sc1 + sh1, 0.f)
                    + fmaxf(u2.y * sc1 + sh1, 0.f) + fmaxf(u3.y * sc1 + sh1, 0.f);
            } else {
                a0 += u0.x + u1.x + u2.x + u3.x;
                a1 += u0.y + u1.y + u2.y + u3.y;
            }
        }
        for (; j < m; ++j) {
            int r = __shfl(idx, j, 64);
            float2 u = *(const float2*)(in + (size_t)r * 128 + c);
            if (BN) { a0 += fmaxf(u.x * sc0 + sh0, 0.f); a1 += fmaxf(u.y * sc1 + sh1, 0.f); }
            else    { a0 += u.x; a1 += u.y; }
        }
    }
    ushort_t h0 = f2bf(a0), h1 = f2bf(a1);
    ushort_t l0 = f2bf(a0 - bf2f(h0)), l1 = f2bf(a1 - bf2f(h1));
    size_t o = (size_t)wave * 128 + c;
    ushort_t* ph = out_hi + o; ph[0] = h0; ph[1] = h1;
    ushort_t* pl = out_lo + o; pl[0] = l0; pl[1] = l1;
}

// ---------------- GEMM: 32x32x16 bf16 MFMA, hi/lo split (3 mfma per k-step) --------
// block = 256 threads = 4 waves; wave w owns cols [32w,32w+32); W frags in registers.
__global__ __launch_bounds__(256) void k_gemm1(
    const ushort_t* __restrict__ a_hi, const ushort_t* __restrict__ a_lo,
    const float* __restrict__ W, const float* __restrict__ bias,
    ushort_t* __restrict__ o_hi, ushort_t* __restrict__ o_lo, int M, int ntiles) {
    int lane = threadIdx.x & 63;
    int wv = threadIdx.x >> 6;
    int c0 = wv * 32;
    int col = c0 + (lane & 31);
    int khalf = (lane >> 5) * 8;

    s16x8 bh[8], bl[8];
#pragma unroll
    for (int ks = 0; ks < 8; ++ks) {
#pragma unroll
        for (int j = 0; j < 8; ++j) {
            float v = W[(ks * 16 + khalf + j) * 128 + col];
            ushort_t h = f2bf(v);
            bh[ks][j] = (short)h;
            bl[ks][j] = (short)f2bf(v - bf2f(h));
        }
    }
    float bv = bias[col];

    for (int tile = blockIdx.x; tile < ntiles; tile += gridDim.x) {
        int m0 = tile * 32;
        int arow = m0 + (lane & 31); if (arow >= M) arow = M - 1;
        const ushort_t* pa = a_hi + (size_t)arow * 128 + khalf;
        const ushort_t* pl = a_lo + (size_t)arow * 128 + khalf;
        f32x16 acc = {}, acc2 = {};
#pragma unroll
        for (int ks = 0; ks < 8; ++ks) {
            s16x8 ah = *(const s16x8*)(pa + ks * 16);
            s16x8 al = *(const s16x8*)(pl + ks * 16);
            acc  = __builtin_amdgcn_mfma_f32_32x32x16_bf16(ah, bh[ks], acc, 0, 0, 0);
            acc2 = __builtin_amdgcn_mfma_f32_32x32x16_bf16(ah, bl[ks], acc2, 0, 0, 0);
            acc2 = __builtin_amdgcn_mfma_f32_32x32x16_bf16(al, bh[ks], acc2, 0, 0, 0);
        }
#pragma unroll
        for (int r = 0; r < 16; ++r) {
            int row = m0 + (r & 3) + 8 * (r >> 2) + 4 * (lane >> 5);
            if (row < M) {
                float v = acc[r] + acc2[r] + bv;
                v = fmaxf(v, 0.f);
                ushort_t h = f2bf(v);
                o_hi[(size_t)row * 128 + col] = h;
                o_lo[(size_t)row * 128 + col] = f2bf(v - bf2f(h));
            }
        }
    }
}

__global__ __launch_bounds__(256) void k_gemm2(
    const ushort_t* __restrict__ a_hi, const ushort_t* __restrict__ a_lo,
    const float* __restrict__ W, const float* __restrict__ bias,
    float* __restrict__ h2, float* __restrict__ stats, int M, int ntiles) {
    int lane = threadIdx.x & 63;
    int wv = threadIdx.x >> 6;
    int c0 = wv * 32;
    int col = c0 + (lane & 31);
    int khalf = (lane >> 5) * 8;

    s16x8 bh[8], bl[8];
#pragma unroll
    for (int ks = 0; ks < 8; ++ks) {
#pragma unroll
        for (int j = 0; j < 8; ++j) {
            float v = W[(ks * 16 + khalf + j) * 128 + col];
            ushort_t h = f2bf(v);
            bh[ks][j] = (short)h;
            bl[ks][j] = (short)f2bf(v - bf2f(h));
        }
    }
    float bv = bias[col];
    float ssum = 0.f, ssq = 0.f;

    for (int tile = blockIdx.x; tile < ntiles; tile += gridDim.x) {
        int m0 = tile * 32;
        int arow = m0 + (lane & 31); if (arow >= M) arow = M - 1;
        const ushort_t* pa = a_hi + (size_t)arow * 128 + khalf;
        const ushort_t* pl = a_lo + (size_t)arow * 128 + khalf;
        f32x16 acc = {}, acc2 = {};
#pragma unroll
        for (int ks = 0; ks < 8; ++ks) {
            s16x8 ah = *(const s16x8*)(pa + ks * 16);
            s16x8 al = *(const s16x8*)(pl + ks * 16);
            acc  = __builtin_amdgcn_mfma_f32_32x32x16_bf16(ah, bh[ks], acc, 0, 0, 0);
            acc2 = __builtin_amdgcn_mfma_f32_32x32x16_bf16(ah, bl[ks], acc2, 0, 0, 0);
            acc2 = __builtin_amdgcn_mfma_f32_32x32x16_bf16(al, bh[ks], acc2, 0, 0, 0);
        }
#pragma unroll
        for (int r = 0; r < 16; ++r) {
            int row = m0 + (r & 3) + 8 * (r >> 2) + 4 * (lane >> 5);
            if (row < M) {
                float v = acc[r] + acc2[r] + bv;
                h2[(size_t)row * 128 + col] = v;
                ssum += v; ssq += v * v;
            }
        }
    }
    atomicAdd(&stats[col], ssum);
    atomicAdd(&stats[128 + col], ssq);
}

__global__ void k_bnfinal(const float* __restrict__ stats, const float* __restrict__ gamma,
                          const float* __restrict__ beta, float invN,
                          float* __restrict__ scale, float* __restrict__ shift) {
    int c = threadIdx.x;  // 128
    float mean = stats[c] * invN;
    float var = stats[128 + c] * invN - mean * mean;
    float sc = gamma[c] * rsqrtf(var + BN_EPS);
    scale[c] = sc;
    shift[c] = beta[c] - mean * sc;
}

__global__ void k_bnapply(const float* __restrict__ h2, const float* __restrict__ scale,
                          const float* __restrict__ shift, float* __restrict__ out, int n4) {
    int i = blockIdx.x * blockDim.x + threadIdx.x;
    int st = gridDim.x * blockDim.x;
    for (; i < n4; i += st) {
        float4 v = ((const float4*)h2)[i];
        int c = (i << 2) & 127;
        v.x = fmaxf(v.x * scale[c + 0] + shift[c + 0], 0.f);
        v.y = fmaxf(v.y * scale[c + 1] + shift[c + 1], 0.f);
        v.z = fmaxf(v.z * scale[c + 2] + shift[c + 2], 0.f);
        v.w = fmaxf(v.w * scale[c + 3] + shift[c + 3], 0.f);
        ((float4*)out)[i] = v;
    }
}

extern "C" void kernel_launch(void* const* d_in, const int* in_sizes, int n_in,
                              void* d_out, int out_size, void* d_ws, size_t ws_size,
                              hipStream_t stream) {
    const float* x      = (const float*)d_in[0];
    const int*   ei     = (const int*)d_in[1];    // int32 per harness convention
    const float* w1_0   = (const float*)d_in[2];
    const float* b1_0   = (const float*)d_in[3];
    const float* w2_0   = (const float*)d_in[4];
    const float* b2_0   = (const float*)d_in[5];
    const float* gamma0 = (const float*)d_in[6];
    const float* beta0  = (const float*)d_in[7];
    const float* w1_1   = (const float*)d_in[8];
    const float* b1_1   = (const float*)d_in[9];
    const float* w2_1   = (const float*)d_in[10];
    const float* b2_1   = (const float*)d_in[11];
    const float* gamma1 = (const float*)d_in[12];
    const float* beta1  = (const float*)d_in[13];

    const int N = in_sizes[0] / 128;
    const int E = in_sizes[1] / 2;
    const int* srcI = ei;
    const int* dstI = ei + E;

    // workspace layout (all offsets 256B-aligned)
    char* p = (char*)d_ws;
    size_t planeB = (size_t)N * 128 * 2;           // 25.6 MB
    ushort_t* a_hi  = (ushort_t*)p; p += planeB;
    ushort_t* a_lo  = (ushort_t*)p; p += planeB;
    ushort_t* h1_hi = (ushort_t*)p; p += planeB;
    ushort_t* h1_lo = (ushort_t*)p; p += planeB;
    float* h2       = (float*)p;    p += (size_t)N * 128 * 4;
    int* rowstart   = (int*)p;      p += ((size_t)(N + 1) * 4 + 255) / 256 * 256;
    int* cursor     = (int*)p;      p += ((size_t)N * 4 + 255) / 256 * 256;
    int* deg        = (int*)p;      p += ((size_t)N * 4 + 255) / 256 * 256;
    int* bsum       = (int*)p;      p += 512;
    int* csr        = (int*)p;      p += ((size_t)E * 4 + 255) / 256 * 256;
    float* stats    = (float*)p;    p += 2048;      // 2 layers x 256 floats
    float* scales   = (float*)p;    p += 2048;      // 2 layers x {scale[128], shift[128]}
    float* scale0 = scales, *shift0 = scales + 128;
    float* scale1 = scales + 256, *shift1 = scales + 384;
    float* stats0 = stats, *stats1 = stats + 256;

    const int NB = (N + 1023) >> 10;
    const int ntiles = (N + 31) / 32;
    float* out = (float*)d_out;

    hipMemsetAsync(deg, 0, (size_t)N * 4, stream);
    hipMemsetAsync(stats, 0, 2048, stream);

    // CSR build (shared by both layers)
    k_deg<<<2048, 256, 0, stream>>>(dstI, E, deg);
    k_blocksum<<<NB, 256, 0, stream>>>(deg, N, bsum);
    k_scanbsum<<<1, 128, 0, stream>>>(bsum, NB, rowstart, N);
    k_localscan<<<NB, 256, 0, stream>>>(deg, N, bsum, rowstart, cursor);
    k_fill<<<2048, 256, 0, stream>>>(srcI, dstI, E, cursor, csr);

    int aggBlocks = (N + 3) / 4;

    // ---- layer 0 ----
    k_agg<false><<<aggBlocks, 256, 0, stream>>>(x, N, rowstart, csr, nullptr, nullptr, a_hi, a_lo);
    k_gemm1<<<768, 256, 0, stream>>>(a_hi, a_lo, w1_0, b1_0, h1_hi, h1_lo, N, ntiles);
    k_gemm2<<<768, 256, 0, stream>>>(h1_hi, h1_lo, w2_0, b2_0, h2, stats0, N, ntiles);
    k_bnfinal<<<1, 128, 0, stream>>>(stats0, gamma0, beta0, 1.0f / (float)N, scale0, shift0);

    // ---- layer 1 (BN+ReLU of layer 0 fused into the gather) ----
    k_agg<true><<<aggBlocks, 256, 0, stream>>>(h2, N, rowstart, csr, scale0, shift0, a_hi, a_lo);
    k_gemm1<<<768, 256, 0, stream>>>(a_hi, a_lo, w1_1, b1_1, h1_hi, h1_lo, N, ntiles);
    k_gemm2<<<768, 256, 0, stream>>>(h1_hi, h1_lo, w2_1, b2_1, h2, stats1, N, ntiles);
    k_bnfinal<<<1, 128, 0, stream>>>(stats1, gamma1, beta1, 1.0f / (float)N, scale1, shift1);
    k_bnapply<<<2048, 256, 0, stream>>>(h2, scale1, shift1, out, N * 128 / 4);
}

// Round 6
// 548.088 us; speedup vs baseline: 1.5985x; 1.5985x over previous
//
#include <hip/hip_runtime.h>
#include <stdint.h>

#define BN_EPS 1e-5f
#define CHUNK 4096

typedef __attribute__((ext_vector_type(8))) short s16x8;
typedef __attribute__((ext_vector_type(16))) float f32x16;
typedef __attribute__((ext_vector_type(4))) unsigned short u16x4;
typedef unsigned short ushort_t;

__device__ __forceinline__ ushort_t f2bf(float x) {
    uint32_t u = __float_as_uint(x);
    u += 0x7fff + ((u >> 16) & 1);   // round-to-nearest-even
    return (ushort_t)(u >> 16);
}
__device__ __forceinline__ float bf2f(ushort_t h) {
    return __uint_as_float(((uint32_t)h) << 16);
}

// ---------------- weight prep: f32 [k][col] -> bf16 hi/lo planes TRANSPOSED [col][k] ----
__global__ void k_wprep(const float* __restrict__ w0, const float* __restrict__ w1,
                        const float* __restrict__ w2, const float* __restrict__ w3,
                        ushort_t* __restrict__ wpl) {
    int mat = blockIdx.x >> 6;
    const float* w = (mat == 0) ? w0 : (mat == 1) ? w1 : (mat == 2) ? w2 : w3;
    int e = ((blockIdx.x & 63) << 8) + threadIdx.x;   // 0..16383
    int k = e >> 7, col = e & 127;
    float v = w[e];
    ushort_t h = f2bf(v);
    ushort_t l = f2bf(v - bf2f(h));
    ushort_t* base = wpl + (size_t)mat * 32768;
    base[col * 128 + k] = h;
    base[16384 + col * 128 + k] = l;
}

// ---------------- binned CSR build ----------------
// phase 1: bin edges by dst>>10 into NBUK bucket arrays, packed (src<<10)|(dst&1023)
__global__ __launch_bounds__(256) void k_bin(const int* __restrict__ src, const int* __restrict__ dst,
                                             int E, int NBUK, int CAP,
                                             int* __restrict__ gcursor, uint32_t* __restrict__ binned) {
    __shared__ int hist[128], excl[128], gbase[128], hA[128], hB[128];
    __shared__ uint32_t pbuf[CHUNK];
    __shared__ unsigned char bbuf[CHUNK];
    int t = threadIdx.x;
    int base = blockIdx.x * CHUNK;
    int cnt = E - base; if (cnt > CHUNK) cnt = CHUNK;

    uint32_t pk[16]; int bk[16]; int loc[16];
    if (t < 128) hist[t] = 0;
    __syncthreads();
#pragma unroll
    for (int k = 0; k < 16; ++k) {
        int j = t + (k << 8);
        bk[k] = -1;
        if (j < cnt) {
            int s = src[base + j], d = dst[base + j];
            bk[k] = d >> 10;
            pk[k] = ((uint32_t)s << 10) | (uint32_t)(d & 1023);
            loc[k] = atomicAdd(&hist[bk[k]], 1);
        }
    }
    __syncthreads();
    // exclusive scan of hist over NBUK (<=128)
    if (t < 128) hA[t] = (t < NBUK) ? hist[t] : 0;
    __syncthreads();
    {
        int cb = 0;
        int* bufs[2] = {hA, hB};
        for (int off = 1; off < 128; off <<= 1) {
            int* A = bufs[cb]; int* B = bufs[cb ^ 1];
            if (t < 128) B[t] = A[t] + ((t >= off) ? A[t - off] : 0);
            __syncthreads();
            cb ^= 1;
        }
        if (t < 128) excl[t] = bufs[cb][t] - ((t < NBUK) ? hist[t] : 0);
    }
    if (t < NBUK && hist[t] > 0) gbase[t] = atomicAdd(&gcursor[t], hist[t]);
    __syncthreads();
    // reorder chunk into LDS, bucket-contiguous
#pragma unroll
    for (int k = 0; k < 16; ++k) {
        if (bk[k] >= 0) {
            int slot = excl[bk[k]] + loc[k];
            pbuf[slot] = pk[k];
            bbuf[slot] = (unsigned char)bk[k];
        }
    }
    __syncthreads();
    // coalesced write-out: consecutive slots -> consecutive global positions per bucket
    for (int j = t; j < cnt; j += 256) {
        int b = bbuf[j];
        int pos = gbase[b] + (j - excl[b]);
        if (pos < CAP) binned[(size_t)b * CAP + pos] = pbuf[j];
    }
}

// phase 2: exclusive scan of bucket counts -> bucketBase; rowstart[N]=E
__global__ void k_bucketscan(const int* __restrict__ gcursor, int NBUK,
                             int* __restrict__ bucketBase, int* __restrict__ rowstart,
                             int N, int E) {
    __shared__ int hA[128], hB[128];
    int t = threadIdx.x;   // 128
    int v = (t < NBUK) ? gcursor[t] : 0;
    hA[t] = v;
    __syncthreads();
    int cb = 0;
    int* bufs[2] = {hA, hB};
    for (int off = 1; off < 128; off <<= 1) {
        int* A = bufs[cb]; int* B = bufs[cb ^ 1];
        B[t] = A[t] + ((t >= off) ? A[t - off] : 0);
        __syncthreads();
        cb ^= 1;
    }
    if (t < NBUK) bucketBase[t] = bufs[cb][t] - v;
    if (t == 0) rowstart[N] = E;
}

// phase 3: per bucket (1 block, 1024 threads): LDS degree hist + scan + dense fill
__global__ __launch_bounds__(1024) void k_bucketcsr(const uint32_t* __restrict__ binned,
                                                    const int* __restrict__ gcursor,
                                                    const int* __restrict__ bucketBase,
                                                    int CAP, int N,
                                                    int* __restrict__ rowstart, int* __restrict__ csr) {
    __shared__ int deg[1024], sA[1024], sB[1024], cur[1024];
    int b = blockIdx.x, t = threadIdx.x;
    int cnt = gcursor[b]; if (cnt > CAP) cnt = CAP;
    int gb = bucketBase[b];
    int nodeBase = b << 10;
    int nloc = N - nodeBase; if (nloc > 1024) nloc = 1024;
    const uint32_t* eb = binned + (size_t)b * CAP;

    deg[t] = 0;
    __syncthreads();
    for (int j = t; j < cnt; j += 1024) atomicAdd(&deg[eb[j] & 1023], 1);
    __syncthreads();
    sA[t] = deg[t];
    __syncthreads();
    int cb2 = 0;
    int* bufs[2] = {sA, sB};
    for (int off = 1; off < 1024; off <<= 1) {
        int* A = bufs[cb2]; int* B = bufs[cb2 ^ 1];
        B[t] = A[t] + ((t >= off) ? A[t - off] : 0);
        __syncthreads();
        cb2 ^= 1;
    }
    int ex = bufs[cb2][t] - deg[t];
    cur[t] = ex;
    if (t < nloc) rowstart[nodeBase + t] = gb + ex;
    __syncthreads();
    for (int j = t; j < cnt; j += 1024) {
        uint32_t e = eb[j];
        int p = atomicAdd(&cur[e & 1023], 1);
        csr[gb + p] = (int)(e >> 10);   // dense writes within this bucket's contiguous segment
    }
}

// ---------------- aggregation: out = f(in[n]) + sum_nbr f(in[s]) ----------------
// one wave per node; half-wave per neighbor row, float4 per lane (16B), 4 rows in flight
template <bool BN>
__global__ __launch_bounds__(256) void k_agg(const float* __restrict__ in, int N,
                                             const int* __restrict__ rowstart, const int* __restrict__ csr,
                                             const float* __restrict__ stats, const float* __restrict__ gamma,
                                             const float* __restrict__ beta, float invN,
                                             ushort_t* __restrict__ out_hi, ushort_t* __restrict__ out_lo) {
    int node = (int)((blockIdx.x * (size_t)blockDim.x + threadIdx.x) >> 6);
    int lane = threadIdx.x & 63;
    int half = lane >> 5, li = lane & 31, ch4 = li << 2;
    if (node >= N) return;

    float scx = 1.f, scy = 1.f, scz = 1.f, scw = 1.f;
    float shx = 0.f, shy = 0.f, shz = 0.f, shw = 0.f;
    if (BN) {
        float4 m4 = *(const float4*)(stats + ch4);
        float4 q4 = *(const float4*)(stats + 128 + ch4);
        float4 g4 = *(const float4*)(gamma + ch4);
        float4 b4 = *(const float4*)(beta + ch4);
        float mx = m4.x * invN, my = m4.y * invN, mz = m4.z * invN, mw = m4.w * invN;
        scx = g4.x * rsqrtf(q4.x * invN - mx * mx + BN_EPS);
        scy = g4.y * rsqrtf(q4.y * invN - my * my + BN_EPS);
        scz = g4.z * rsqrtf(q4.z * invN - mz * mz + BN_EPS);
        scw = g4.w * rsqrtf(q4.w * invN - mw * mw + BN_EPS);
        shx = b4.x - mx * scx; shy = b4.y - my * scy;
        shz = b4.z - mz * scz; shw = b4.w - mw * scw;
    }

    float ax = 0.f, ay = 0.f, az = 0.f, aw = 0.f;
    if (half == 0) {
        float4 v = *(const float4*)(in + (size_t)node * 128 + ch4);
        if (BN) {
            ax = fmaxf(v.x * scx + shx, 0.f); ay = fmaxf(v.y * scy + shy, 0.f);
            az = fmaxf(v.z * scz + shz, 0.f); aw = fmaxf(v.w * scw + shw, 0.f);
        } else { ax = v.x; ay = v.y; az = v.z; aw = v.w; }
    }

    int s0 = rowstart[node], s1 = rowstart[node + 1];
    for (int base2 = s0; base2 < s1; base2 += 64) {
        int m = s1 - base2; if (m > 64) m = 64;
        int idx = (lane < m) ? csr[base2 + lane] : 0;
        for (int j = 0; j < m; j += 8) {
            int r0 = __shfl(idx, j + half, 64);
            int r1 = __shfl(idx, j + 2 + half, 64);
            int r2 = __shfl(idx, j + 4 + half, 64);
            int r3 = __shfl(idx, j + 6 + half, 64);
            float4 u0 = *(const float4*)(in + (size_t)r0 * 128 + ch4);
            float4 u1 = *(const float4*)(in + (size_t)r1 * 128 + ch4);
            float4 u2 = *(const float4*)(in + (size_t)r2 * 128 + ch4);
            float4 u3 = *(const float4*)(in + (size_t)r3 * 128 + ch4);
            if (j + half < m) {
                if (BN) { ax += fmaxf(u0.x*scx+shx,0.f); ay += fmaxf(u0.y*scy+shy,0.f); az += fmaxf(u0.z*scz+shz,0.f); aw += fmaxf(u0.w*scw+shw,0.f); }
                else    { ax += u0.x; ay += u0.y; az += u0.z; aw += u0.w; }
            }
            if (j + 2 + half < m) {
                if (BN) { ax += fmaxf(u1.x*scx+shx,0.f); ay += fmaxf(u1.y*scy+shy,0.f); az += fmaxf(u1.z*scz+shz,0.f); aw += fmaxf(u1.w*scw+shw,0.f); }
                else    { ax += u1.x; ay += u1.y; az += u1.z; aw += u1.w; }
            }
            if (j + 4 + half < m) {
                if (BN) { ax += fmaxf(u2.x*scx+shx,0.f); ay += fmaxf(u2.y*scy+shy,0.f); az += fmaxf(u2.z*scz+shz,0.f); aw += fmaxf(u2.w*scw+shw,0.f); }
                else    { ax += u2.x; ay += u2.y; az += u2.z; aw += u2.w; }
            }
            if (j + 6 + half < m) {
                if (BN) { ax += fmaxf(u3.x*scx+shx,0.f); ay += fmaxf(u3.y*scy+shy,0.f); az += fmaxf(u3.z*scz+shz,0.f); aw += fmaxf(u3.w*scw+shw,0.f); }
                else    { ax += u3.x; ay += u3.y; az += u3.z; aw += u3.w; }
            }
        }
    }
    // combine half-waves (lane ^ 32 has same channels, other neighbor parity)
    ax += __shfl(ax, lane ^ 32, 64);
    ay += __shfl(ay, lane ^ 32, 64);
    az += __shfl(az, lane ^ 32, 64);
    aw += __shfl(aw, lane ^ 32, 64);
    if (half == 0) {
        u16x4 hi, lo;
        ushort_t h;
        h = f2bf(ax); hi[0] = h; lo[0] = f2bf(ax - bf2f(h));
        h = f2bf(ay); hi[1] = h; lo[1] = f2bf(ay - bf2f(h));
        h = f2bf(az); hi[2] = h; lo[2] = f2bf(az - bf2f(h));
        h = f2bf(aw); hi[3] = h; lo[3] = f2bf(aw - bf2f(h));
        size_t o = (size_t)node * 128 + ch4;
        *(u16x4*)(out_hi + o) = hi;
        *(u16x4*)(out_lo + o) = lo;
    }
}

// ---------------- fused MLP: relu(A@W1+b1)@W2+b2, + per-col sum/sumsq ----------------
// 256 thr = 4 waves; wave w owns cols [32w,32w+32); h1 tile in XOR-swizzled LDS.
__global__ __launch_bounds__(256) void k_mlp(const ushort_t* __restrict__ a_hi, const ushort_t* __restrict__ a_lo,
                                             const ushort_t* __restrict__ w1pl, const ushort_t* __restrict__ w2pl,
                                             const float* __restrict__ bias1, const float* __restrict__ bias2,
                                             float* __restrict__ h2, float* __restrict__ stats,
                                             int M, int ntiles) {
    __shared__ float4 tile[1024];   // 16 KB: [row 0..31][chunk 0..31], chunk XOR-swizzled by row
    int lane = threadIdx.x & 63;
    int wv = threadIdx.x >> 6;
    int li = lane & 31, half = lane >> 5;
    int c0 = wv << 5;
    int col = c0 + li;
    int khalf = half << 3;
    float* tf = (float*)tile;

    s16x8 b1h[8], b1l[8];
#pragma unroll
    for (int ks = 0; ks < 8; ++ks) {
        b1h[ks] = *(const s16x8*)(w1pl + (size_t)col * 128 + ks * 16 + khalf);
        b1l[ks] = *(const s16x8*)(w1pl + 16384 + (size_t)col * 128 + ks * 16 + khalf);
    }
    float b1v = bias1[col], b2v = bias2[col];
    float ssum = 0.f, ssq = 0.f;

    for (int ti = blockIdx.x; ti < ntiles; ti += gridDim.x) {
        int m0 = ti << 5;
        int arow = m0 + li; if (arow >= M) arow = M - 1;
        const ushort_t* pa = a_hi + (size_t)arow * 128 + khalf;
        const ushort_t* pl = a_lo + (size_t)arow * 128 + khalf;
        f32x16 acc = {}, acc2 = {};
#pragma unroll
        for (int ks = 0; ks < 8; ++ks) {
            s16x8 ah = *(const s16x8*)(pa + ks * 16);
            s16x8 al = *(const s16x8*)(pl + ks * 16);
            acc  = __builtin_amdgcn_mfma_f32_32x32x16_bf16(ah, b1h[ks], acc, 0, 0, 0);
            acc2 = __builtin_amdgcn_mfma_f32_32x32x16_bf16(ah, b1l[ks], acc2, 0, 0, 0);
            acc2 = __builtin_amdgcn_mfma_f32_32x32x16_bf16(al, b1h[ks], acc2, 0, 0, 0);
        }
        // epilogue 1: bias+relu -> swizzled LDS tile (conflict-free writes)
#pragma unroll
        for (int r = 0; r < 16; ++r) {
            int row = (r & 3) + ((r >> 2) << 3) + (half << 2);
            float v = fmaxf(acc[r] + acc2[r] + b1v, 0.f);
            int chunk = (col >> 2) ^ row;
            tf[((row << 5) + chunk) * 4 + (col & 3)] = v;
        }
        __syncthreads();
        // GEMM2: A = h1 tile from LDS (conflict-free b128 reads), bf16 split on the fly
        acc = (f32x16){}; acc2 = (f32x16){};
#pragma unroll
        for (int ks = 0; ks < 8; ++ks) {
            int k0 = ks * 16 + khalf;
            float4 fA = tile[(li << 5) + (((k0 >> 2) + 0) ^ li)];
            float4 fB = tile[(li << 5) + (((k0 >> 2) + 1) ^ li)];
            s16x8 ah, al;
            float vv[8] = {fA.x, fA.y, fA.z, fA.w, fB.x, fB.y, fB.z, fB.w};
#pragma unroll
            for (int q = 0; q < 8; ++q) {
                ushort_t hh = f2bf(vv[q]);
                ah[q] = (short)hh;
                al[q] = (short)f2bf(vv[q] - bf2f(hh));
            }
            s16x8 b2h = *(const s16x8*)(w2pl + (size_t)col * 128 + k0);
            s16x8 b2l = *(const s16x8*)(w2pl + 16384 + (size_t)col * 128 + k0);
            acc  = __builtin_amdgcn_mfma_f32_32x32x16_bf16(ah, b2h, acc, 0, 0, 0);
            acc2 = __builtin_amdgcn_mfma_f32_32x32x16_bf16(ah, b2l, acc2, 0, 0, 0);
            acc2 = __builtin_amdgcn_mfma_f32_32x32x16_bf16(al, b2h, acc2, 0, 0, 0);
        }
        __syncthreads();   // LDS consumed; safe for next tile's writes
        // epilogue 2: bias, store f32, accumulate stats
#pragma unroll
        for (int r = 0; r < 16; ++r) {
            int row = m0 + (r & 3) + ((r >> 2) << 3) + (half << 2);
            if (row < M) {
                float v = acc[r] + acc2[r] + b2v;
                h2[(size_t)row * 128 + col] = v;
                ssum += v; ssq += v * v;
            }
        }
    }
    ssum += __shfl(ssum, lane ^ 32, 64);
    ssq  += __shfl(ssq,  lane ^ 32, 64);
    if (half == 0) {
        atomicAdd(&stats[col], ssum);
        atomicAdd(&stats[128 + col], ssq);
    }
}

// ---------------- final BN + ReLU (scale/shift computed per block from stats) --------
__global__ __launch_bounds__(256) void k_bnapply(const float* __restrict__ h2, const float* __restrict__ stats,
                                                 const float* __restrict__ gamma, const float* __restrict__ beta,
                                                 float invN, float* __restrict__ out, int n4) {
    __shared__ float sc[128], sh[128];
    int t = threadIdx.x;
    if (t < 128) {
        float mean = stats[t] * invN;
        float var = stats[128 + t] * invN - mean * mean;
        float s = gamma[t] * rsqrtf(var + BN_EPS);
        sc[t] = s; sh[t] = beta[t] - mean * s;
    }
    __syncthreads();
    int i = blockIdx.x * 256 + t, st = gridDim.x * 256;
    for (; i < n4; i += st) {
        float4 v = ((const float4*)h2)[i];
        int c = (i << 2) & 127;
        v.x = fmaxf(v.x * sc[c + 0] + sh[c + 0], 0.f);
        v.y = fmaxf(v.y * sc[c + 1] + sh[c + 1], 0.f);
        v.z = fmaxf(v.z * sc[c + 2] + sh[c + 2], 0.f);
        v.w = fmaxf(v.w * sc[c + 3] + sh[c + 3], 0.f);
        ((float4*)out)[i] = v;
    }
}

extern "C" void kernel_launch(void* const* d_in, const int* in_sizes, int n_in,
                              void* d_out, int out_size, void* d_ws, size_t ws_size,
                              hipStream_t stream) {
    const float* x      = (const float*)d_in[0];
    const int*   ei     = (const int*)d_in[1];
    const float* w1_0   = (const float*)d_in[2];
    const float* b1_0   = (const float*)d_in[3];
    const float* w2_0   = (const float*)d_in[4];
    const float* b2_0   = (const float*)d_in[5];
    const float* gamma0 = (const float*)d_in[6];
    const float* beta0  = (const float*)d_in[7];
    const float* w1_1   = (const float*)d_in[8];
    const float* b1_1   = (const float*)d_in[9];
    const float* w2_1   = (const float*)d_in[10];
    const float* b2_1   = (const float*)d_in[11];
    const float* gamma1 = (const float*)d_in[12];
    const float* beta1  = (const float*)d_in[13];

    const int N = in_sizes[0] / 128;
    const int E = in_sizes[1] / 2;
    const int* srcI = ei;
    const int* dstI = ei + E;
    const int NBUK = (N + 1023) >> 10;                       // 98 (<=128 required)
    const int CAP  = (((E / NBUK) + 2048) + 255) & ~255;     // 16σ slack, uniform dst

    char* p = (char*)d_ws;
    auto aup = [](size_t v) { return (v + 255) & ~(size_t)255; };
    ushort_t* a_hi   = (ushort_t*)p; p += aup((size_t)N * 128 * 2);
    ushort_t* a_lo   = (ushort_t*)p; p += aup((size_t)N * 128 * 2);
    float*    h2     = (float*)p;    p += aup((size_t)N * 128 * 4);
    int*      rowstart = (int*)p;    p += aup((size_t)(N + 1) * 4);
    int*      csr    = (int*)p;      p += aup((size_t)E * 4);
    uint32_t* binned = (uint32_t*)p; p += aup((size_t)NBUK * CAP * 4);
    ushort_t* wpl    = (ushort_t*)p; p += aup((size_t)4 * 32768 * 2);
    int*      bucketBase = (int*)p;  p += 512;
    int*      gcursor = (int*)p;                      // zero region: 512B cursors + 2KB stats
    float*    stats0  = (float*)(p + 512);
    float*    stats1  = stats0 + 256;
    hipMemsetAsync(gcursor, 0, 512 + 2048, stream);

    const int ntiles = (N + 31) / 32;
    const float invN = 1.0f / (float)N;
    float* out = (float*)d_out;

    k_wprep<<<256, 256, 0, stream>>>(w1_0, w2_0, w1_1, w2_1, wpl);
    k_bin<<<(E + CHUNK - 1) / CHUNK, 256, 0, stream>>>(srcI, dstI, E, NBUK, CAP, gcursor, binned);
    k_bucketscan<<<1, 128, 0, stream>>>(gcursor, NBUK, bucketBase, rowstart, N, E);
    k_bucketcsr<<<NBUK, 1024, 0, stream>>>(binned, gcursor, bucketBase, CAP, N, rowstart, csr);

    int aggBlocks = (N + 3) / 4;
    // ---- layer 0 ----
    k_agg<false><<<aggBlocks, 256, 0, stream>>>(x, N, rowstart, csr, nullptr, nullptr, nullptr, 0.f, a_hi, a_lo);
    k_mlp<<<782, 256, 0, stream>>>(a_hi, a_lo, wpl, wpl + 32768, b1_0, b2_0, h2, stats0, N, ntiles);
    // ---- layer 1 (layer-0 BN+ReLU fused into gather; bnfinal folded in) ----
    k_agg<true><<<aggBlocks, 256, 0, stream>>>(h2, N, rowstart, csr, stats0, gamma0, beta0, invN, a_hi, a_lo);
    k_mlp<<<782, 256, 0, stream>>>(a_hi, a_lo, wpl + 65536, wpl + 98304, b1_1, b2_1, h2, stats1, N, ntiles);
    k_bnapply<<<2048, 256, 0, stream>>>(h2, stats1, gamma1, beta1, invN, out, N * 32);
}

// Round 7
// 463.385 us; speedup vs baseline: 1.8907x; 1.1828x over previous
//
#include <hip/hip_runtime.h>
#include <stdint.h>

#define BN_EPS 1e-5f
#define CHUNK 4096

typedef __attribute__((ext_vector_type(8))) short s16x8;
typedef __attribute__((ext_vector_type(16))) float f32x16;
typedef __attribute__((ext_vector_type(4))) unsigned short u16x4;
typedef unsigned short ushort_t;
typedef _Float16 f16;
typedef __attribute__((ext_vector_type(4))) _Float16 f16x4;

__device__ __forceinline__ ushort_t f2bf(float x) {
    uint32_t u = __float_as_uint(x);
    u += 0x7fff + ((u >> 16) & 1);   // round-to-nearest-even
    return (ushort_t)(u >> 16);
}
__device__ __forceinline__ float bf2f(ushort_t h) {
    return __uint_as_float(((uint32_t)h) << 16);
}

// ---------------- weight prep: f32 [k][col] -> bf16 hi/lo planes TRANSPOSED [col][k] ----
__global__ void k_wprep(const float* __restrict__ w0, const float* __restrict__ w1,
                        const float* __restrict__ w2, const float* __restrict__ w3,
                        ushort_t* __restrict__ wpl) {
    int mat = blockIdx.x >> 6;
    const float* w = (mat == 0) ? w0 : (mat == 1) ? w1 : (mat == 2) ? w2 : w3;
    int e = ((blockIdx.x & 63) << 8) + threadIdx.x;   // 0..16383
    int k = e >> 7, col = e & 127;
    float v = w[e];
    ushort_t h = f2bf(v);
    ushort_t l = f2bf(v - bf2f(h));
    ushort_t* base = wpl + (size_t)mat * 32768;
    base[col * 128 + k] = h;
    base[16384 + col * 128 + k] = l;
}

// ---------------- fp16 gather-plane prep ----------------
// layer 0: xh = fp16(x)
__global__ void k_x0(const float* __restrict__ in, f16* __restrict__ out, int n4) {
    int i = blockIdx.x * blockDim.x + threadIdx.x;
    int st = gridDim.x * blockDim.x;
    for (; i < n4; i += st) {
        float4 v = ((const float4*)in)[i];
        f16x4 h;
        h[0] = (f16)v.x; h[1] = (f16)v.y; h[2] = (f16)v.z; h[3] = (f16)v.w;
        ((f16x4*)out)[i] = h;
    }
}

// layer 1: x1h = fp16(relu(bn(h2)))  — BN folded here, out of the gather hot loop
__global__ __launch_bounds__(256) void k_x1(const float* __restrict__ h2, const float* __restrict__ stats,
                                            const float* __restrict__ gamma, const float* __restrict__ beta,
                                            float invN, f16* __restrict__ out, int n4) {
    __shared__ float sc[128], sh[128];
    int t = threadIdx.x;
    if (t < 128) {
        float mean = stats[t] * invN;
        float var = stats[128 + t] * invN - mean * mean;
        float s = gamma[t] * rsqrtf(var + BN_EPS);
        sc[t] = s; sh[t] = beta[t] - mean * s;
    }
    __syncthreads();
    int i = blockIdx.x * 256 + t, st = gridDim.x * 256;
    for (; i < n4; i += st) {
        float4 v = ((const float4*)h2)[i];
        int c = (i << 2) & 127;
        f16x4 h;
        h[0] = (f16)fmaxf(v.x * sc[c + 0] + sh[c + 0], 0.f);
        h[1] = (f16)fmaxf(v.y * sc[c + 1] + sh[c + 1], 0.f);
        h[2] = (f16)fmaxf(v.z * sc[c + 2] + sh[c + 2], 0.f);
        h[3] = (f16)fmaxf(v.w * sc[c + 3] + sh[c + 3], 0.f);
        ((f16x4*)out)[i] = h;
    }
}

// ---------------- binned CSR build ----------------
// phase 1: bin edges by dst>>10 into NBUK bucket arrays, packed (src<<10)|(dst&1023)
__global__ __launch_bounds__(256) void k_bin(const int* __restrict__ src, const int* __restrict__ dst,
                                             int E, int NBUK, int CAP,
                                             int* __restrict__ gcursor, uint32_t* __restrict__ binned) {
    __shared__ int hist[128], excl[128], gbase[128], hA[128], hB[128];
    __shared__ uint32_t pbuf[CHUNK];
    __shared__ unsigned char bbuf[CHUNK];
    int t = threadIdx.x;
    int base = blockIdx.x * CHUNK;
    int cnt = E - base; if (cnt > CHUNK) cnt = CHUNK;

    uint32_t pk[16]; int bk[16]; int loc[16];
    if (t < 128) hist[t] = 0;
    __syncthreads();
#pragma unroll
    for (int k = 0; k < 16; ++k) {
        int j = t + (k << 8);
        bk[k] = -1;
        if (j < cnt) {
            int s = src[base + j], d = dst[base + j];
            bk[k] = d >> 10;
            pk[k] = ((uint32_t)s << 10) | (uint32_t)(d & 1023);
            loc[k] = atomicAdd(&hist[bk[k]], 1);
        }
    }
    __syncthreads();
    if (t < 128) hA[t] = (t < NBUK) ? hist[t] : 0;
    __syncthreads();
    {
        int cb = 0;
        int* bufs[2] = {hA, hB};
        for (int off = 1; off < 128; off <<= 1) {
            int* A = bufs[cb]; int* B = bufs[cb ^ 1];
            if (t < 128) B[t] = A[t] + ((t >= off) ? A[t - off] : 0);
            __syncthreads();
            cb ^= 1;
        }
        if (t < 128) excl[t] = bufs[cb][t] - ((t < NBUK) ? hist[t] : 0);
    }
    if (t < NBUK && hist[t] > 0) gbase[t] = atomicAdd(&gcursor[t], hist[t]);
    __syncthreads();
#pragma unroll
    for (int k = 0; k < 16; ++k) {
        if (bk[k] >= 0) {
            int slot = excl[bk[k]] + loc[k];
            pbuf[slot] = pk[k];
            bbuf[slot] = (unsigned char)bk[k];
        }
    }
    __syncthreads();
    for (int j = t; j < cnt; j += 256) {
        int b = bbuf[j];
        int pos = gbase[b] + (j - excl[b]);
        if (pos < CAP) binned[(size_t)b * CAP + pos] = pbuf[j];
    }
}

// phase 2: exclusive scan of bucket counts -> bucketBase; rowstart[N]=E
__global__ void k_bucketscan(const int* __restrict__ gcursor, int NBUK,
                             int* __restrict__ bucketBase, int* __restrict__ rowstart,
                             int N, int E) {
    __shared__ int hA[128], hB[128];
    int t = threadIdx.x;   // 128
    int v = (t < NBUK) ? gcursor[t] : 0;
    hA[t] = v;
    __syncthreads();
    int cb = 0;
    int* bufs[2] = {hA, hB};
    for (int off = 1; off < 128; off <<= 1) {
        int* A = bufs[cb]; int* B = bufs[cb ^ 1];
        B[t] = A[t] + ((t >= off) ? A[t - off] : 0);
        __syncthreads();
        cb ^= 1;
    }
    if (t < NBUK) bucketBase[t] = bufs[cb][t] - v;
    if (t == 0) rowstart[N] = E;
}

// phase 3: per bucket (1 block, 1024 threads): LDS degree hist + scan + dense fill
__global__ __launch_bounds__(1024) void k_bucketcsr(const uint32_t* __restrict__ binned,
                                                    const int* __restrict__ gcursor,
                                                    const int* __restrict__ bucketBase,
                                                    int CAP, int N,
                                                    int* __restrict__ rowstart, int* __restrict__ csr) {
    __shared__ int deg[1024], sA[1024], sB[1024], cur[1024];
    int b = blockIdx.x, t = threadIdx.x;
    int cnt = gcursor[b]; if (cnt > CAP) cnt = CAP;
    int gb = bucketBase[b];
    int nodeBase = b << 10;
    int nloc = N - nodeBase; if (nloc > 1024) nloc = 1024;
    const uint32_t* eb = binned + (size_t)b * CAP;

    deg[t] = 0;
    __syncthreads();
    for (int j = t; j < cnt; j += 1024) atomicAdd(&deg[eb[j] & 1023], 1);
    __syncthreads();
    sA[t] = deg[t];
    __syncthreads();
    int cb2 = 0;
    int* bufs[2] = {sA, sB};
    for (int off = 1; off < 1024; off <<= 1) {
        int* A = bufs[cb2]; int* B = bufs[cb2 ^ 1];
        B[t] = A[t] + ((t >= off) ? A[t - off] : 0);
        __syncthreads();
        cb2 ^= 1;
    }
    int ex = bufs[cb2][t] - deg[t];
    cur[t] = ex;
    if (t < nloc) rowstart[nodeBase + t] = gb + ex;
    __syncthreads();
    for (int j = t; j < cnt; j += 1024) {
        uint32_t e = eb[j];
        int p = atomicAdd(&cur[e & 1023], 1);
        csr[gb + p] = (int)(e >> 10);
    }
}

// ---------------- aggregation: out = plane[n] + sum_nbr plane[s]  (plane = fp16) --------
// one wave per node; half-wave per neighbor row (256B), f16x4 per lane, 4 rows in flight
__global__ __launch_bounds__(256) void k_agg(const f16* __restrict__ plane, int N,
                                             const int* __restrict__ rowstart, const int* __restrict__ csr,
                                             ushort_t* __restrict__ out_hi, ushort_t* __restrict__ out_lo) {
    int node = (int)((blockIdx.x * (size_t)blockDim.x + threadIdx.x) >> 6);
    int lane = threadIdx.x & 63;
    int half = lane >> 5, li = lane & 31, ch4 = li << 2;
    if (node >= N) return;

    float ax = 0.f, ay = 0.f, az = 0.f, aw = 0.f;
    if (half == 0) {
        f16x4 sv = *(const f16x4*)(plane + (size_t)node * 128 + ch4);
        ax = (float)sv[0]; ay = (float)sv[1]; az = (float)sv[2]; aw = (float)sv[3];
    }

    int s0 = rowstart[node], s1 = rowstart[node + 1];
    for (int base2 = s0; base2 < s1; base2 += 64) {
        int m = s1 - base2; if (m > 64) m = 64;
        int idx = (lane < m) ? csr[base2 + lane] : 0;
        for (int j = 0; j < m; j += 8) {
            int r0 = __shfl(idx, j + half, 64);
            int r1 = __shfl(idx, j + 2 + half, 64);
            int r2 = __shfl(idx, j + 4 + half, 64);
            int r3 = __shfl(idx, j + 6 + half, 64);
            f16x4 u0 = *(const f16x4*)(plane + (size_t)r0 * 128 + ch4);
            f16x4 u1 = *(const f16x4*)(plane + (size_t)r1 * 128 + ch4);
            f16x4 u2 = *(const f16x4*)(plane + (size_t)r2 * 128 + ch4);
            f16x4 u3 = *(const f16x4*)(plane + (size_t)r3 * 128 + ch4);
            if (j + half < m)     { ax += (float)u0[0]; ay += (float)u0[1]; az += (float)u0[2]; aw += (float)u0[3]; }
            if (j + 2 + half < m) { ax += (float)u1[0]; ay += (float)u1[1]; az += (float)u1[2]; aw += (float)u1[3]; }
            if (j + 4 + half < m) { ax += (float)u2[0]; ay += (float)u2[1]; az += (float)u2[2]; aw += (float)u2[3]; }
            if (j + 6 + half < m) { ax += (float)u3[0]; ay += (float)u3[1]; az += (float)u3[2]; aw += (float)u3[3]; }
        }
    }
    // combine half-waves (lane ^ 32 has same channels, other neighbor parity)
    ax += __shfl(ax, lane ^ 32, 64);
    ay += __shfl(ay, lane ^ 32, 64);
    az += __shfl(az, lane ^ 32, 64);
    aw += __shfl(aw, lane ^ 32, 64);
    if (half == 0) {
        u16x4 hi, lo;
        ushort_t h;
        h = f2bf(ax); hi[0] = h; lo[0] = f2bf(ax - bf2f(h));
        h = f2bf(ay); hi[1] = h; lo[1] = f2bf(ay - bf2f(h));
        h = f2bf(az); hi[2] = h; lo[2] = f2bf(az - bf2f(h));
        h = f2bf(aw); hi[3] = h; lo[3] = f2bf(aw - bf2f(h));
        size_t o = (size_t)node * 128 + ch4;
        *(u16x4*)(out_hi + o) = hi;
        *(u16x4*)(out_lo + o) = lo;
    }
}

// ---------------- fused MLP: relu(A@W1+b1)@W2+b2, + per-col sum/sumsq ----------------
// 256 thr = 4 waves; wave w owns cols [32w,32w+32); h1 tile in XOR-swizzled LDS.
__global__ __launch_bounds__(256) void k_mlp(const ushort_t* __restrict__ a_hi, const ushort_t* __restrict__ a_lo,
                                             const ushort_t* __restrict__ w1pl, const ushort_t* __restrict__ w2pl,
                                             const float* __restrict__ bias1, const float* __restrict__ bias2,
                                             float* __restrict__ h2, float* __restrict__ stats,
                                             int M, int ntiles) {
    __shared__ float4 tile[1024];   // 16 KB: [row 0..31][chunk 0..31], chunk XOR-swizzled by row
    int lane = threadIdx.x & 63;
    int wv = threadIdx.x >> 6;
    int li = lane & 31, half = lane >> 5;
    int c0 = wv << 5;
    int col = c0 + li;
    int khalf = half << 3;
    float* tf = (float*)tile;

    s16x8 b1h[8], b1l[8];
#pragma unroll
    for (int ks = 0; ks < 8; ++ks) {
        b1h[ks] = *(const s16x8*)(w1pl + (size_t)col * 128 + ks * 16 + khalf);
        b1l[ks] = *(const s16x8*)(w1pl + 16384 + (size_t)col * 128 + ks * 16 + khalf);
    }
    float b1v = bias1[col], b2v = bias2[col];
    float ssum = 0.f, ssq = 0.f;

    for (int ti = blockIdx.x; ti < ntiles; ti += gridDim.x) {
        int m0 = ti << 5;
        int arow = m0 + li; if (arow >= M) arow = M - 1;
        const ushort_t* pa = a_hi + (size_t)arow * 128 + khalf;
        const ushort_t* pl = a_lo + (size_t)arow * 128 + khalf;
        f32x16 acc = {}, acc2 = {};
#pragma unroll
        for (int ks = 0; ks < 8; ++ks) {
            s16x8 ah = *(const s16x8*)(pa + ks * 16);
            s16x8 al = *(const s16x8*)(pl + ks * 16);
            acc  = __builtin_amdgcn_mfma_f32_32x32x16_bf16(ah, b1h[ks], acc, 0, 0, 0);
            acc2 = __builtin_amdgcn_mfma_f32_32x32x16_bf16(ah, b1l[ks], acc2, 0, 0, 0);
            acc2 = __builtin_amdgcn_mfma_f32_32x32x16_bf16(al, b1h[ks], acc2, 0, 0, 0);
        }
#pragma unroll
        for (int r = 0; r < 16; ++r) {
            int row = (r & 3) + ((r >> 2) << 3) + (half << 2);
            float v = fmaxf(acc[r] + acc2[r] + b1v, 0.f);
            int chunk = (col >> 2) ^ row;
            tf[((row << 5) + chunk) * 4 + (col & 3)] = v;
        }
        __syncthreads();
        acc = (f32x16){}; acc2 = (f32x16){};
#pragma unroll
        for (int ks = 0; ks < 8; ++ks) {
            int k0 = ks * 16 + khalf;
            float4 fA = tile[(li << 5) + (((k0 >> 2) + 0) ^ li)];
            float4 fB = tile[(li << 5) + (((k0 >> 2) + 1) ^ li)];
            s16x8 ah, al;
            float vv[8] = {fA.x, fA.y, fA.z, fA.w, fB.x, fB.y, fB.z, fB.w};
#pragma unroll
            for (int q = 0; q < 8; ++q) {
                ushort_t hh = f2bf(vv[q]);
                ah[q] = (short)hh;
                al[q] = (short)f2bf(vv[q] - bf2f(hh));
            }
            s16x8 b2h = *(const s16x8*)(w2pl + (size_t)col * 128 + k0);
            s16x8 b2l = *(const s16x8*)(w2pl + 16384 + (size_t)col * 128 + k0);
            acc  = __builtin_amdgcn_mfma_f32_32x32x16_bf16(ah, b2h, acc, 0, 0, 0);
            acc2 = __builtin_amdgcn_mfma_f32_32x32x16_bf16(ah, b2l, acc2, 0, 0, 0);
            acc2 = __builtin_amdgcn_mfma_f32_32x32x16_bf16(al, b2h, acc2, 0, 0, 0);
        }
        __syncthreads();
#pragma unroll
        for (int r = 0; r < 16; ++r) {
            int row = m0 + (r & 3) + ((r >> 2) << 3) + (half << 2);
            if (row < M) {
                float v = acc[r] + acc2[r] + b2v;
                h2[(size_t)row * 128 + col] = v;
                ssum += v; ssq += v * v;
            }
        }
    }
    ssum += __shfl(ssum, lane ^ 32, 64);
    ssq  += __shfl(ssq,  lane ^ 32, 64);
    if (half == 0) {
        atomicAdd(&stats[col], ssum);
        atomicAdd(&stats[128 + col], ssq);
    }
}

// ---------------- final BN + ReLU ----------------
__global__ __launch_bounds__(256) void k_bnapply(const float* __restrict__ h2, const float* __restrict__ stats,
                                                 const float* __restrict__ gamma, const float* __restrict__ beta,
                                                 float invN, float* __restrict__ out, int n4) {
    __shared__ float sc[128], sh[128];
    int t = threadIdx.x;
    if (t < 128) {
        float mean = stats[t] * invN;
        float var = stats[128 + t] * invN - mean * mean;
        float s = gamma[t] * rsqrtf(var + BN_EPS);
        sc[t] = s; sh[t] = beta[t] - mean * s;
    }
    __syncthreads();
    int i = blockIdx.x * 256 + t, st = gridDim.x * 256;
    for (; i < n4; i += st) {
        float4 v = ((const float4*)h2)[i];
        int c = (i << 2) & 127;
        v.x = fmaxf(v.x * sc[c + 0] + sh[c + 0], 0.f);
        v.y = fmaxf(v.y * sc[c + 1] + sh[c + 1], 0.f);
        v.z = fmaxf(v.z * sc[c + 2] + sh[c + 2], 0.f);
        v.w = fmaxf(v.w * sc[c + 3] + sh[c + 3], 0.f);
        ((float4*)out)[i] = v;
    }
}

extern "C" void kernel_launch(void* const* d_in, const int* in_sizes, int n_in,
                              void* d_out, int out_size, void* d_ws, size_t ws_size,
                              hipStream_t stream) {
    const float* x      = (const float*)d_in[0];
    const int*   ei     = (const int*)d_in[1];
    const float* w1_0   = (const float*)d_in[2];
    const float* b1_0   = (const float*)d_in[3];
    const float* w2_0   = (const float*)d_in[4];
    const float* b2_0   = (const float*)d_in[5];
    const float* gamma0 = (const float*)d_in[6];
    const float* beta0  = (const float*)d_in[7];
    const float* w1_1   = (const float*)d_in[8];
    const float* b1_1   = (const float*)d_in[9];
    const float* w2_1   = (const float*)d_in[10];
    const float* b2_1   = (const float*)d_in[11];
    const float* gamma1 = (const float*)d_in[12];
    const float* beta1  = (const float*)d_in[13];

    const int N = in_sizes[0] / 128;
    const int E = in_sizes[1] / 2;
    const int* srcI = ei;
    const int* dstI = ei + E;
    const int NBUK = (N + 1023) >> 10;                       // 98 (<=128 required)
    const int CAP  = (((E / NBUK) + 2048) + 255) & ~255;     // 16σ slack, uniform dst

    char* p = (char*)d_ws;
    auto aup = [](size_t v) { return (v + 255) & ~(size_t)255; };
    ushort_t* a_hi   = (ushort_t*)p; p += aup((size_t)N * 128 * 2);
    ushort_t* a_lo   = (ushort_t*)p; p += aup((size_t)N * 128 * 2);
    float*    h2     = (float*)p;    p += aup((size_t)N * 128 * 4);
    f16*      xh     = (f16*)p;      p += aup((size_t)N * 128 * 2);   // fp16 gather plane (reused for layer 1)
    int*      rowstart = (int*)p;    p += aup((size_t)(N + 1) * 4);
    int*      csr    = (int*)p;      p += aup((size_t)E * 4);
    uint32_t* binned = (uint32_t*)p; p += aup((size_t)NBUK * CAP * 4);
    ushort_t* wpl    = (ushort_t*)p; p += aup((size_t)4 * 32768 * 2);
    int*      bucketBase = (int*)p;  p += 512;
    int*      gcursor = (int*)p;                      // zero region: 512B cursors + 2KB stats
    float*    stats0  = (float*)(p + 512);
    float*    stats1  = stats0 + 256;
    hipMemsetAsync(gcursor, 0, 512 + 2048, stream);

    const int ntiles = (N + 31) / 32;
    const float invN = 1.0f / (float)N;
    float* out = (float*)d_out;

    k_wprep<<<256, 256, 0, stream>>>(w1_0, w2_0, w1_1, w2_1, wpl);
    k_x0<<<2048, 256, 0, stream>>>(x, xh, N * 32);
    k_bin<<<(E + CHUNK - 1) / CHUNK, 256, 0, stream>>>(srcI, dstI, E, NBUK, CAP, gcursor, binned);
    k_bucketscan<<<1, 128, 0, stream>>>(gcursor, NBUK, bucketBase, rowstart, N, E);
    k_bucketcsr<<<NBUK, 1024, 0, stream>>>(binned, gcursor, bucketBase, CAP, N, rowstart, csr);

    int aggBlocks = (N + 3) / 4;
    // ---- layer 0 ----
    k_agg<<<aggBlocks, 256, 0, stream>>>(xh, N, rowstart, csr, a_hi, a_lo);
    k_mlp<<<782, 256, 0, stream>>>(a_hi, a_lo, wpl, wpl + 32768, b1_0, b2_0, h2, stats0, N, ntiles);
    // ---- layer 1: BN+ReLU folded into fp16 plane prep; gather is pure fp16 ----
    k_x1<<<2048, 256, 0, stream>>>(h2, stats0, gamma0, beta0, invN, xh, N * 32);
    k_agg<<<aggBlocks, 256, 0, stream>>>(xh, N, rowstart, csr, a_hi, a_lo);
    k_mlp<<<782, 256, 0, stream>>>(a_hi, a_lo, wpl + 65536, wpl + 98304, b1_1, b2_1, h2, stats1, N, ntiles);
    k_bnapply<<<2048, 256, 0, stream>>>(h2, stats1, gamma1, beta1, invN, out, N * 32);
}

// Round 8
// 446.367 us; speedup vs baseline: 1.9628x; 1.0381x over previous
//
#include <hip/hip_runtime.h>
#include <stdint.h>

#define BN_EPS 1e-5f
#define CHUNK 4096

typedef __attribute__((ext_vector_type(8))) short s16x8;
typedef __attribute__((ext_vector_type(16))) float f32x16;
typedef __attribute__((ext_vector_type(4))) unsigned short u16x4;
typedef unsigned short ushort_t;
typedef _Float16 f16;
typedef __attribute__((ext_vector_type(4))) _Float16 f16x4;

__device__ __forceinline__ ushort_t f2bf(float x) {
    uint32_t u = __float_as_uint(x);
    u += 0x7fff + ((u >> 16) & 1);   // round-to-nearest-even
    return (ushort_t)(u >> 16);
}
__device__ __forceinline__ float bf2f(ushort_t h) {
    return __uint_as_float(((uint32_t)h) << 16);
}

// ---------------- weight prep: f32 [k][col] -> bf16 hi/lo planes TRANSPOSED [col][k] ----
__global__ void k_wprep(const float* __restrict__ w0, const float* __restrict__ w1,
                        const float* __restrict__ w2, const float* __restrict__ w3,
                        ushort_t* __restrict__ wpl) {
    int mat = blockIdx.x >> 6;
    const float* w = (mat == 0) ? w0 : (mat == 1) ? w1 : (mat == 2) ? w2 : w3;
    int e = ((blockIdx.x & 63) << 8) + threadIdx.x;   // 0..16383
    int k = e >> 7, col = e & 127;
    float v = w[e];
    ushort_t h = f2bf(v);
    ushort_t l = f2bf(v - bf2f(h));
    ushort_t* base = wpl + (size_t)mat * 32768;
    base[col * 128 + k] = h;
    base[16384 + col * 128 + k] = l;
}

// ---------------- fp16 gather-plane prep ----------------
__global__ void k_x0(const float* __restrict__ in, f16* __restrict__ out, int n4) {
    int i = blockIdx.x * blockDim.x + threadIdx.x;
    int st = gridDim.x * blockDim.x;
    for (; i < n4; i += st) {
        float4 v = ((const float4*)in)[i];
        f16x4 h;
        h[0] = (f16)v.x; h[1] = (f16)v.y; h[2] = (f16)v.z; h[3] = (f16)v.w;
        ((f16x4*)out)[i] = h;
    }
}

__global__ __launch_bounds__(256) void k_x1(const float* __restrict__ h2, const float* __restrict__ stats,
                                            const float* __restrict__ gamma, const float* __restrict__ beta,
                                            float invN, f16* __restrict__ out, int n4) {
    __shared__ float sc[128], sh[128];
    int t = threadIdx.x;
    if (t < 128) {
        float mean = stats[t] * invN;
        float var = stats[128 + t] * invN - mean * mean;
        float s = gamma[t] * rsqrtf(var + BN_EPS);
        sc[t] = s; sh[t] = beta[t] - mean * s;
    }
    __syncthreads();
    int i = blockIdx.x * 256 + t, st = gridDim.x * 256;
    for (; i < n4; i += st) {
        float4 v = ((const float4*)h2)[i];
        int c = (i << 2) & 127;
        f16x4 h;
        h[0] = (f16)fmaxf(v.x * sc[c + 0] + sh[c + 0], 0.f);
        h[1] = (f16)fmaxf(v.y * sc[c + 1] + sh[c + 1], 0.f);
        h[2] = (f16)fmaxf(v.z * sc[c + 2] + sh[c + 2], 0.f);
        h[3] = (f16)fmaxf(v.w * sc[c + 3] + sh[c + 3], 0.f);
        ((f16x4*)out)[i] = h;
    }
}

// ---------------- binned CSR build ----------------
__global__ __launch_bounds__(256) void k_bin(const int* __restrict__ src, const int* __restrict__ dst,
                                             int E, int NBUK, int CAP,
                                             int* __restrict__ gcursor, uint32_t* __restrict__ binned) {
    __shared__ int hist[128], excl[128], gbase[128], hA[128], hB[128];
    __shared__ uint32_t pbuf[CHUNK];
    __shared__ unsigned char bbuf[CHUNK];
    int t = threadIdx.x;
    int base = blockIdx.x * CHUNK;
    int cnt = E - base; if (cnt > CHUNK) cnt = CHUNK;

    uint32_t pk[16]; int bk[16]; int loc[16];
    if (t < 128) hist[t] = 0;
    __syncthreads();
#pragma unroll
    for (int k = 0; k < 16; ++k) {
        int j = t + (k << 8);
        bk[k] = -1;
        if (j < cnt) {
            int s = src[base + j], d = dst[base + j];
            bk[k] = d >> 10;
            pk[k] = ((uint32_t)s << 10) | (uint32_t)(d & 1023);
            loc[k] = atomicAdd(&hist[bk[k]], 1);
        }
    }
    __syncthreads();
    if (t < 128) hA[t] = (t < NBUK) ? hist[t] : 0;
    __syncthreads();
    {
        int cb = 0;
        int* bufs[2] = {hA, hB};
        for (int off = 1; off < 128; off <<= 1) {
            int* A = bufs[cb]; int* B = bufs[cb ^ 1];
            if (t < 128) B[t] = A[t] + ((t >= off) ? A[t - off] : 0);
            __syncthreads();
            cb ^= 1;
        }
        if (t < 128) excl[t] = bufs[cb][t] - ((t < NBUK) ? hist[t] : 0);
    }
    if (t < NBUK && hist[t] > 0) gbase[t] = atomicAdd(&gcursor[t], hist[t]);
    __syncthreads();
#pragma unroll
    for (int k = 0; k < 16; ++k) {
        if (bk[k] >= 0) {
            int slot = excl[bk[k]] + loc[k];
            pbuf[slot] = pk[k];
            bbuf[slot] = (unsigned char)bk[k];
        }
    }
    __syncthreads();
    for (int j = t; j < cnt; j += 256) {
        int b = bbuf[j];
        int pos = gbase[b] + (j - excl[b]);
        if (pos < CAP) binned[(size_t)b * CAP + pos] = pbuf[j];
    }
}

__global__ void k_bucketscan(const int* __restrict__ gcursor, int NBUK,
                             int* __restrict__ bucketBase, int* __restrict__ rowstart,
                             int N, int E) {
    __shared__ int hA[128], hB[128];
    int t = threadIdx.x;   // 128
    int v = (t < NBUK) ? gcursor[t] : 0;
    hA[t] = v;
    __syncthreads();
    int cb = 0;
    int* bufs[2] = {hA, hB};
    for (int off = 1; off < 128; off <<= 1) {
        int* A = bufs[cb]; int* B = bufs[cb ^ 1];
        B[t] = A[t] + ((t >= off) ? A[t - off] : 0);
        __syncthreads();
        cb ^= 1;
    }
    if (t < NBUK) bucketBase[t] = bufs[cb][t] - v;
    if (t == 0) rowstart[N] = E;
}

__global__ __launch_bounds__(1024) void k_bucketcsr(const uint32_t* __restrict__ binned,
                                                    const int* __restrict__ gcursor,
                                                    const int* __restrict__ bucketBase,
                                                    int CAP, int N,
                                                    int* __restrict__ rowstart, int* __restrict__ csr) {
    __shared__ int deg[1024], sA[1024], sB[1024], cur[1024];
    int b = blockIdx.x, t = threadIdx.x;
    int cnt = gcursor[b]; if (cnt > CAP) cnt = CAP;
    int gb = bucketBase[b];
    int nodeBase = b << 10;
    int nloc = N - nodeBase; if (nloc > 1024) nloc = 1024;
    const uint32_t* eb = binned + (size_t)b * CAP;

    deg[t] = 0;
    __syncthreads();
    for (int j = t; j < cnt; j += 1024) atomicAdd(&deg[eb[j] & 1023], 1);
    __syncthreads();
    sA[t] = deg[t];
    __syncthreads();
    int cb2 = 0;
    int* bufs[2] = {sA, sB};
    for (int off = 1; off < 1024; off <<= 1) {
        int* A = bufs[cb2]; int* B = bufs[cb2 ^ 1];
        B[t] = A[t] + ((t >= off) ? A[t - off] : 0);
        __syncthreads();
        cb2 ^= 1;
    }
    int ex = bufs[cb2][t] - deg[t];
    cur[t] = ex;
    if (t < nloc) rowstart[nodeBase + t] = gb + ex;
    __syncthreads();
    for (int j = t; j < cnt; j += 1024) {
        uint32_t e = eb[j];
        int p = atomicAdd(&cur[e & 1023], 1);
        csr[gb + p] = (int)(e >> 10);
    }
}

// ---------------- aggregation: out = plane[n] + sum_nbr plane[s]  (plane = fp16) --------
__global__ __launch_bounds__(256) void k_agg(const f16* __restrict__ plane, int N,
                                             const int* __restrict__ rowstart, const int* __restrict__ csr,
                                             ushort_t* __restrict__ out_hi, ushort_t* __restrict__ out_lo) {
    int node = (int)((blockIdx.x * (size_t)blockDim.x + threadIdx.x) >> 6);
    int lane = threadIdx.x & 63;
    int half = lane >> 5, li = lane & 31, ch4 = li << 2;
    if (node >= N) return;

    float ax = 0.f, ay = 0.f, az = 0.f, aw = 0.f;
    if (half == 0) {
        f16x4 sv = *(const f16x4*)(plane + (size_t)node * 128 + ch4);
        ax = (float)sv[0]; ay = (float)sv[1]; az = (float)sv[2]; aw = (float)sv[3];
    }

    int s0 = rowstart[node], s1 = rowstart[node + 1];
    for (int base2 = s0; base2 < s1; base2 += 64) {
        int m = s1 - base2; if (m > 64) m = 64;
        int idx = (lane < m) ? csr[base2 + lane] : 0;
        for (int j = 0; j < m; j += 8) {
            int r0 = __shfl(idx, j + half, 64);
            int r1 = __shfl(idx, j + 2 + half, 64);
            int r2 = __shfl(idx, j + 4 + half, 64);
            int r3 = __shfl(idx, j + 6 + half, 64);
            f16x4 u0 = *(const f16x4*)(plane + (size_t)r0 * 128 + ch4);
            f16x4 u1 = *(const f16x4*)(plane + (size_t)r1 * 128 + ch4);
            f16x4 u2 = *(const f16x4*)(plane + (size_t)r2 * 128 + ch4);
            f16x4 u3 = *(const f16x4*)(plane + (size_t)r3 * 128 + ch4);
            if (j + half < m)     { ax += (float)u0[0]; ay += (float)u0[1]; az += (float)u0[2]; aw += (float)u0[3]; }
            if (j + 2 + half < m) { ax += (float)u1[0]; ay += (float)u1[1]; az += (float)u1[2]; aw += (float)u1[3]; }
            if (j + 4 + half < m) { ax += (float)u2[0]; ay += (float)u2[1]; az += (float)u2[2]; aw += (float)u2[3]; }
            if (j + 6 + half < m) { ax += (float)u3[0]; ay += (float)u3[1]; az += (float)u3[2]; aw += (float)u3[3]; }
        }
    }
    ax += __shfl(ax, lane ^ 32, 64);
    ay += __shfl(ay, lane ^ 32, 64);
    az += __shfl(az, lane ^ 32, 64);
    aw += __shfl(aw, lane ^ 32, 64);
    if (half == 0) {
        u16x4 hi, lo;
        ushort_t h;
        h = f2bf(ax); hi[0] = h; lo[0] = f2bf(ax - bf2f(h));
        h = f2bf(ay); hi[1] = h; lo[1] = f2bf(ay - bf2f(h));
        h = f2bf(az); hi[2] = h; lo[2] = f2bf(az - bf2f(h));
        h = f2bf(aw); hi[3] = h; lo[3] = f2bf(aw - bf2f(h));
        size_t o = (size_t)node * 128 + ch4;
        *(u16x4*)(out_hi + o) = hi;
        *(u16x4*)(out_lo + o) = lo;
    }
}

// ---------------- fused MLP with global_load_lds A-staging ----------------
// LDS per block: A dbuf 2x16KB (hi 8K + lo 8K, chunk-XOR swizzled) + h1 16KB = 48KB.
// A tile staged direct-to-LDS (linear dest, inverse-swizzled global source — rule #21).
// Raw s_barrier + manual waitcnt so the t+1 prefetch is NOT drained mid-tile.
// NOTE: assumes M % 32 == 0 (N=100000 -> 3125 tiles exactly).
__global__ __launch_bounds__(256) void k_mlp(const ushort_t* __restrict__ a_hi, const ushort_t* __restrict__ a_lo,
                                             const ushort_t* __restrict__ w1pl, const ushort_t* __restrict__ w2pl,
                                             const float* __restrict__ bias1, const float* __restrict__ bias2,
                                             float* __restrict__ h2, float* __restrict__ stats,
                                             int M, int ntiles) {
    __shared__ ushort_t lds_a[2][8192];   // per buf: [hi 4096 u16][lo 4096 u16]
    __shared__ ushort_t lds_h1[8192];     // [hi 4096][lo 4096]
    int tid = threadIdx.x;
    int lane = tid & 63;
    int wv = tid >> 6;
    int li = lane & 31, half = lane >> 5;
    int col = (wv << 5) + li;
    int khalf = half << 3;
    int rsw = li & 15;

    // staging lambda: 16 wave-issues of 1KB; LDS byte ob -> row=(ob>>8)&31, csw=(ob>>4)&15,
    // plane=ob>>13; global chunk c = csw ^ (row&15)  (inverse swizzle on the SOURCE)
    auto stage_a = [&](int m0, ushort_t* buf) {
        int w = tid >> 6, l = tid & 63;
#pragma unroll
        for (int i = 0; i < 4; ++i) {
            int u = w + (i << 2);                 // 1KB unit 0..15
            int ob = (u << 10) + (l << 4);        // this lane's LDS byte
            int plane = ob >> 13;
            int r = (ob >> 8) & 31;
            int csw = (ob >> 4) & 15;
            int c = csw ^ (r & 15);
            const ushort_t* g = (plane ? a_lo : a_hi) + (((size_t)(m0 + r)) << 7) + (c << 3);
            __builtin_amdgcn_global_load_lds(g, buf + (u << 9), 16, 0, 0);  // u<<9 ushorts = u KB
        }
    };

    s16x8 b1h[8], b1l[8];
#pragma unroll
    for (int ks = 0; ks < 8; ++ks) {
        b1h[ks] = *(const s16x8*)(w1pl + (size_t)col * 128 + ks * 16 + khalf);
        b1l[ks] = *(const s16x8*)(w1pl + 16384 + (size_t)col * 128 + ks * 16 + khalf);
    }
    float b1v = bias1[col], b2v = bias2[col];
    float ssum = 0.f, ssq = 0.f;

    int cur = 0;
    stage_a(blockIdx.x << 5, lds_a[0]);
    asm volatile("s_waitcnt vmcnt(0)" ::: "memory");
    __builtin_amdgcn_sched_barrier(0);
    __builtin_amdgcn_s_barrier();

    for (int ti = blockIdx.x; ti < ntiles; ti += gridDim.x) {
        int m0 = ti << 5;
        int tn = ti + (int)gridDim.x;
        if (tn < ntiles) stage_a(tn << 5, lds_a[cur ^ 1]);   // prefetch next tile (stays in flight)

        // GEMM1: A from LDS (swizzled), B = W1 regs
        const ushort_t* A = lds_a[cur];
        f32x16 acc = {}, acc2 = {};
#pragma unroll
        for (int ks = 0; ks < 8; ++ks) {
            int csw = ((ks << 1) + half) ^ rsw;
            s16x8 ah = *(const s16x8*)(A + (li << 7) + (csw << 3));
            s16x8 al = *(const s16x8*)(A + 4096 + (li << 7) + (csw << 3));
            acc  = __builtin_amdgcn_mfma_f32_32x32x16_bf16(ah, b1h[ks], acc, 0, 0, 0);
            acc2 = __builtin_amdgcn_mfma_f32_32x32x16_bf16(ah, b1l[ks], acc2, 0, 0, 0);
            acc2 = __builtin_amdgcn_mfma_f32_32x32x16_bf16(al, b1h[ks], acc2, 0, 0, 0);
        }
        // epilogue 1: bias+relu, split to bf16 hi/lo, write swizzled LDS
        int cch = col >> 3, cw = col & 7;
#pragma unroll
        for (int r = 0; r < 16; ++r) {
            int row = (r & 3) + ((r >> 2) << 3) + (half << 2);
            float v = fmaxf(acc[r] + acc2[r] + b1v, 0.f);
            ushort_t hh = f2bf(v);
            ushort_t ll = f2bf(v - bf2f(hh));
            int o = (row << 7) + ((cch ^ (row & 15)) << 3) + cw;
            lds_h1[o] = hh;
            lds_h1[4096 + o] = ll;
        }
        asm volatile("s_waitcnt lgkmcnt(0)" ::: "memory");   // h1 writes committed (NOT vmcnt!)
        __builtin_amdgcn_sched_barrier(0);
        __builtin_amdgcn_s_barrier();

        // GEMM2: A = h1 from LDS, B = W2 from global (L2-hot)
        acc = (f32x16){}; acc2 = (f32x16){};
#pragma unroll
        for (int ks = 0; ks < 8; ++ks) {
            int csw = ((ks << 1) + half) ^ rsw;
            s16x8 ah = *(const s16x8*)(lds_h1 + (li << 7) + (csw << 3));
            s16x8 al = *(const s16x8*)(lds_h1 + 4096 + (li << 7) + (csw << 3));
            int k0 = (ks << 4) + khalf;
            s16x8 b2h = *(const s16x8*)(w2pl + (size_t)col * 128 + k0);
            s16x8 b2l = *(const s16x8*)(w2pl + 16384 + (size_t)col * 128 + k0);
            acc  = __builtin_amdgcn_mfma_f32_32x32x16_bf16(ah, b2h, acc, 0, 0, 0);
            acc2 = __builtin_amdgcn_mfma_f32_32x32x16_bf16(ah, b2l, acc2, 0, 0, 0);
            acc2 = __builtin_amdgcn_mfma_f32_32x32x16_bf16(al, b2h, acc2, 0, 0, 0);
        }
        // epilogue 2: bias, f32 store, stats
#pragma unroll
        for (int r = 0; r < 16; ++r) {
            int row = m0 + (r & 3) + ((r >> 2) << 3) + (half << 2);
            float v = acc[r] + acc2[r] + b2v;
            h2[(size_t)row * 128 + col] = v;
            ssum += v; ssq += v * v;
        }
        asm volatile("s_waitcnt vmcnt(0) lgkmcnt(0)" ::: "memory");  // A(t+1) landed; h1 reads done
        __builtin_amdgcn_sched_barrier(0);
        __builtin_amdgcn_s_barrier();
        cur ^= 1;
    }
    ssum += __shfl(ssum, lane ^ 32, 64);
    ssq  += __shfl(ssq,  lane ^ 32, 64);
    if (half == 0) {
        atomicAdd(&stats[col], ssum);
        atomicAdd(&stats[128 + col], ssq);
    }
}

// ---------------- final BN + ReLU ----------------
__global__ __launch_bounds__(256) void k_bnapply(const float* __restrict__ h2, const float* __restrict__ stats,
                                                 const float* __restrict__ gamma, const float* __restrict__ beta,
                                                 float invN, float* __restrict__ out, int n4) {
    __shared__ float sc[128], sh[128];
    int t = threadIdx.x;
    if (t < 128) {
        float mean = stats[t] * invN;
        float var = stats[128 + t] * invN - mean * mean;
        float s = gamma[t] * rsqrtf(var + BN_EPS);
        sc[t] = s; sh[t] = beta[t] - mean * s;
    }
    __syncthreads();
    int i = blockIdx.x * 256 + t, st = gridDim.x * 256;
    for (; i < n4; i += st) {
        float4 v = ((const float4*)h2)[i];
        int c = (i << 2) & 127;
        v.x = fmaxf(v.x * sc[c + 0] + sh[c + 0], 0.f);
        v.y = fmaxf(v.y * sc[c + 1] + sh[c + 1], 0.f);
        v.z = fmaxf(v.z * sc[c + 2] + sh[c + 2], 0.f);
        v.w = fmaxf(v.w * sc[c + 3] + sh[c + 3], 0.f);
        ((float4*)out)[i] = v;
    }
}

extern "C" void kernel_launch(void* const* d_in, const int* in_sizes, int n_in,
                              void* d_out, int out_size, void* d_ws, size_t ws_size,
                              hipStream_t stream) {
    const float* x      = (const float*)d_in[0];
    const int*   ei     = (const int*)d_in[1];
    const float* w1_0   = (const float*)d_in[2];
    const float* b1_0   = (const float*)d_in[3];
    const float* w2_0   = (const float*)d_in[4];
    const float* b2_0   = (const float*)d_in[5];
    const float* gamma0 = (const float*)d_in[6];
    const float* beta0  = (const float*)d_in[7];
    const float* w1_1   = (const float*)d_in[8];
    const float* b1_1   = (const float*)d_in[9];
    const float* w2_1   = (const float*)d_in[10];
    const float* b2_1   = (const float*)d_in[11];
    const float* gamma1 = (const float*)d_in[12];
    const float* beta1  = (const float*)d_in[13];

    const int N = in_sizes[0] / 128;
    const int E = in_sizes[1] / 2;
    const int* srcI = ei;
    const int* dstI = ei + E;
    const int NBUK = (N + 1023) >> 10;                       // 98 (<=128 required)
    const int CAP  = (((E / NBUK) + 2048) + 255) & ~255;     // 16σ slack, uniform dst

    char* p = (char*)d_ws;
    auto aup = [](size_t v) { return (v + 255) & ~(size_t)255; };
    ushort_t* a_hi   = (ushort_t*)p; p += aup((size_t)N * 128 * 2);
    ushort_t* a_lo   = (ushort_t*)p; p += aup((size_t)N * 128 * 2);
    float*    h2     = (float*)p;    p += aup((size_t)N * 128 * 4);
    f16*      xh     = (f16*)p;      p += aup((size_t)N * 128 * 2);   // fp16 gather plane (reused for layer 1)
    int*      rowstart = (int*)p;    p += aup((size_t)(N + 1) * 4);
    int*      csr    = (int*)p;      p += aup((size_t)E * 4);
    uint32_t* binned = (uint32_t*)p; p += aup((size_t)NBUK * CAP * 4);
    ushort_t* wpl    = (ushort_t*)p; p += aup((size_t)4 * 32768 * 2);
    int*      bucketBase = (int*)p;  p += 512;
    int*      gcursor = (int*)p;                      // zero region: 512B cursors + 2KB stats
    float*    stats0  = (float*)(p + 512);
    float*    stats1  = stats0 + 256;
    hipMemsetAsync(gcursor, 0, 512 + 2048, stream);

    const int ntiles = (N + 31) / 32;
    const float invN = 1.0f / (float)N;
    float* out = (float*)d_out;

    k_wprep<<<256, 256, 0, stream>>>(w1_0, w2_0, w1_1, w2_1, wpl);
    k_x0<<<2048, 256, 0, stream>>>(x, xh, N * 32);
    k_bin<<<(E + CHUNK - 1) / CHUNK, 256, 0, stream>>>(srcI, dstI, E, NBUK, CAP, gcursor, binned);
    k_bucketscan<<<1, 128, 0, stream>>>(gcursor, NBUK, bucketBase, rowstart, N, E);
    k_bucketcsr<<<NBUK, 1024, 0, stream>>>(binned, gcursor, bucketBase, CAP, N, rowstart, csr);

    int aggBlocks = (N + 3) / 4;
    // ---- layer 0 ----
    k_agg<<<aggBlocks, 256, 0, stream>>>(xh, N, rowstart, csr, a_hi, a_lo);
    k_mlp<<<768, 256, 0, stream>>>(a_hi, a_lo, wpl, wpl + 32768, b1_0, b2_0, h2, stats0, N, ntiles);
    // ---- layer 1: BN+ReLU folded into fp16 plane prep; gather is pure fp16 ----
    k_x1<<<2048, 256, 0, stream>>>(h2, stats0, gamma0, beta0, invN, xh, N * 32);
    k_agg<<<aggBlocks, 256, 0, stream>>>(xh, N, rowstart, csr, a_hi, a_lo);
    k_mlp<<<768, 256, 0, stream>>>(a_hi, a_lo, wpl + 65536, wpl + 98304, b1_1, b2_1, h2, stats1, N, ntiles);
    k_bnapply<<<2048, 256, 0, stream>>>(h2, stats1, gamma1, beta1, invN, out, N * 32);
}